// Round 1
// 687.359 us; speedup vs baseline: 1.0566x; 1.0566x over previous
//
#include <hip/hip_runtime.h>
#include <cstdint>
#include <cstddef>

typedef _Float16 half8 __attribute__((ext_vector_type(8)));
typedef _Float16 half4 __attribute__((ext_vector_type(4)));
typedef float floatx4 __attribute__((ext_vector_type(4)));

#define BATCH 256
#define NCHK 512
#define NVAR 1024
#define EDGE 3072

// ---- check MLP tiling ----
#define KC    96
#define NT1C  26     // hidden 388 -> 416 -> 26 col-tiles of 16
#define KS1C  3      // GEMM1 K = 96 -> 3 chunks of 32
#define NT2C  6      // out 96 -> 6 tiles of 16
// ---- var MLP tiling ----
#define NT1V  13     // hidden 196 -> 208 -> 13 col-tiles of 16
#define KS1V  2      // GEMM1 K 49 -> 64 -> 2 chunks of 32
#define NT2V  4      // out 49 -> 64 -> 4 tiles of 16

__device__ __forceinline__ float gelu_f(float x) {
  // exact gelu via A&S 7.1.26 erf approx, |err(erf)| < 1.5e-7
  float ax = fabsf(x) * 0.70710678118654752440f;
  float t  = 1.0f / (1.0f + 0.3275911f * ax);
  float p  = t * (0.254829592f + t * (-0.284496736f + t * (1.421413741f +
             t * (-1.453152027f + t * 1.061405429f))));
  float e  = __expf(-ax * ax);
  float erfv = 1.0f - p * e;
  float s  = (x >= 0.0f) ? erfv : -erfv;
  return 0.5f * x * (1.0f + s);
}

// W1 packs: K32 A-operand fragments (16x16x32): frag[(s*NT1+nt)*64+l][j] =
//   W[k = s*32 + (l>>4)*8 + j][n = nt*16 + (l&15)]
// W2 packs: K16 A-operand fragments (16x16x16): frag[(ht*NT2+nt)*64+l][j] =
//   W[k = ht*16 + (l>>4)*4 + j][n = nt*16 + (l&15)]
// (K16 layout matches the 16x16 MFMA C/D layout, so GEMM2 consumes GEMM1's
// gelu'd accumulator directly from registers — no LDS round-trip.)
__global__ void pack_kernel(const float* __restrict__ cW1, const float* __restrict__ cb1,
                            const float* __restrict__ cW2, const float* __restrict__ cb2,
                            const float* __restrict__ vW1, const float* __restrict__ vb1,
                            const float* __restrict__ vW2, const float* __restrict__ vb2,
                            _Float16* __restrict__ w1c, _Float16* __restrict__ w2c,
                            _Float16* __restrict__ w1v, _Float16* __restrict__ w2v,
                            float* __restrict__ b1c, float* __restrict__ w96c,
                            float* __restrict__ b2c, float* __restrict__ b1v,
                            float* __restrict__ b2v)
{
  int id = blockIdx.x * 256 + threadIdx.x;
  const int S0 = KS1C * NT1C * 64;   // 4992  (half8)
  const int S1 = NT1C * NT2C * 64;   // 9984  (half4)
  const int S2 = KS1V * NT1V * 64;   // 1664  (half8)
  const int S3 = NT1V * NT2V * 64;   // 3328  (half4)
  if (id < S0) {
    int s = id / (NT1C * 64), rem = id % (NT1C * 64), nt = rem / 64, l = rem % 64;
    int q = l >> 4, n = nt * 16 + (l & 15);
    half8 v;
    #pragma unroll
    for (int j = 0; j < 8; ++j) {
      int k = s * 32 + q * 8 + j;
      float x = (n < 388) ? cW1[k * 388 + n] : 0.0f;
      v[j] = (_Float16)x;
    }
    *(half8*)(w1c + (size_t)id * 8) = v;
    return;
  }
  id -= S0;
  if (id < S1) {
    int ht = id / (NT2C * 64), rem = id % (NT2C * 64), nt = rem / 64, l = rem % 64;
    int q = l >> 4, n = nt * 16 + (l & 15);
    half4 v;
    #pragma unroll
    for (int j = 0; j < 4; ++j) {
      int k = ht * 16 + q * 4 + j;
      float x = (k < 388) ? cW2[k * 96 + n] : 0.0f;
      v[j] = (_Float16)x;
    }
    *(half4*)(w2c + (size_t)id * 4) = v;
    return;
  }
  id -= S1;
  if (id < S2) {
    int s = id / (NT1V * 64), rem = id % (NT1V * 64), nt = rem / 64, l = rem % 64;
    int q = l >> 4, n = nt * 16 + (l & 15);
    half8 v;
    #pragma unroll
    for (int j = 0; j < 8; ++j) {
      int k = s * 32 + q * 8 + j;                        // row 48 = prior row
      float x = (k < 49 && n < 196) ? vW1[k * 196 + n] : 0.0f;
      v[j] = (_Float16)x;
    }
    *(half8*)(w1v + (size_t)id * 8) = v;
    return;
  }
  id -= S2;
  if (id < S3) {
    int ht = id / (NT2V * 64), rem = id % (NT2V * 64), nt = rem / 64, l = rem % 64;
    int q = l >> 4, n = nt * 16 + (l & 15);
    half4 v;
    #pragma unroll
    for (int j = 0; j < 4; ++j) {
      int k = ht * 16 + q * 4 + j;
      float x = (k < 196 && n < 49) ? vW2[k * 49 + n] : 0.0f;
      v[j] = (_Float16)x;
    }
    *(half4*)(w2v + (size_t)id * 4) = v;
    return;
  }
  id -= S3;
  if (id < 416) { b1c[id]  = (id < 388) ? cb1[id] : 0.0f; return; }
  id -= 416;
  if (id < 416) { w96c[id] = (id < 388) ? cW1[96 * 388 + id] : 0.0f; return; }
  id -= 416;
  if (id < 96)  { b2c[id]  = cb2[id]; return; }
  id -= 96;
  if (id < 208) { b1v[id]  = (id < 196) ? vb1[id] : 0.0f; return; }
  id -= 208;
  if (id < 64)  { b2v[id]  = (id < 49) ? vb2[id] : 0.0f; return; }
}

__global__ void init_kernel(const int* __restrict__ perm, const float* __restrict__ prior,
                            _Float16* __restrict__ Mc)
{
  int t = blockIdx.x * 256 + threadIdx.x;   // t < BATCH*EDGE
  int b = t / EDGE, k = t - b * EDGE;
  int e = perm[k];
  _Float16* dst = Mc + ((size_t)b * EDGE + e) * 16;
  half8 z  = {0,0,0,0,0,0,0,0};
  half8 z0 = z;
  z0[0] = (_Float16)prior[k / 3];
  *(half8*)dst = z0;
  *(half8*)(dst + 8) = z;
}

// Check-node MLP, M=32 rows/wave, transposed GEMMs, zero LDS.
// GEMM1': mfma32(W1frag, Mcfrag) -> D[hid][row]; lane: row = l&15, hid = q*4+r.
// GEMM2': mfma16(W2frag, geluD)  -> D[out][row]; GEMM1's C/D layout IS the
//         K16 B-operand layout, so H never leaves registers.
__global__ __launch_bounds__(256, 4) void kernelC(
    const _Float16* __restrict__ Mc, const int* __restrict__ synd,
    _Float16* __restrict__ Yc,
    const _Float16* __restrict__ W1p, const _Float16* __restrict__ W2p,
    const float* __restrict__ b1, const float* __restrict__ w96,
    const float* __restrict__ b2)
{
  const int tid = threadIdx.x, w = tid >> 6, l = tid & 63;
  const int q = l >> 4, c = l & 15;
  const int r0 = blockIdx.x * 128 + w * 32;

  // Mc fragments (B-operand: lane holds batch-row n = l&15, k = q*8+j)
  half8 mb[2][3];
  float sg[2];
  #pragma unroll
  for (int rg = 0; rg < 2; ++rg) {
    const _Float16* Arow = Mc + (size_t)(r0 + rg * 16 + c) * KC;
    #pragma unroll
    for (int ks = 0; ks < 3; ++ks)
      mb[rg][ks] = *(const half8*)(Arow + ks * 32 + q * 8);
    sg[rg] = 1.0f - 2.0f * (float)synd[r0 + rg * 16 + c];
  }

  floatx4 acc2[2][6];
  #pragma unroll
  for (int rg = 0; rg < 2; ++rg)
    #pragma unroll
    for (int nt = 0; nt < 6; ++nt)
      acc2[rg][nt] = (floatx4){0.f, 0.f, 0.f, 0.f};

  const half8* W1f = (const half8*)W1p;
  const half4* W2f = (const half4*)W2p;

  #pragma unroll 2
  for (int ht = 0; ht < NT1C; ++ht) {
    half8 wa0 = W1f[(0 * NT1C + ht) * 64 + l];
    half8 wa1 = W1f[(1 * NT1C + ht) * 64 + l];
    half8 wa2 = W1f[(2 * NT1C + ht) * 64 + l];
    half4 wf[6];
    #pragma unroll
    for (int nt = 0; nt < 6; ++nt)
      wf[nt] = W2f[(ht * NT2C + nt) * 64 + l];
    floatx4 bia = *(const floatx4*)(b1  + ht * 16 + q * 4);
    floatx4 wsg = *(const floatx4*)(w96 + ht * 16 + q * 4);
    #pragma unroll
    for (int rg = 0; rg < 2; ++rg) {
      floatx4 a = {0.f, 0.f, 0.f, 0.f};
      a = __builtin_amdgcn_mfma_f32_16x16x32_f16(wa0, mb[rg][0], a, 0, 0, 0);
      a = __builtin_amdgcn_mfma_f32_16x16x32_f16(wa1, mb[rg][1], a, 0, 0, 0);
      a = __builtin_amdgcn_mfma_f32_16x16x32_f16(wa2, mb[rg][2], a, 0, 0, 0);
      half4 h;
      #pragma unroll
      for (int r = 0; r < 4; ++r)
        h[r] = (_Float16)gelu_f(a[r] + bia[r] + sg[rg] * wsg[r]);
      #pragma unroll
      for (int nt = 0; nt < 6; ++nt)
        acc2[rg][nt] = __builtin_amdgcn_mfma_f32_16x16x16f16(wf[nt], h, acc2[rg][nt], 0, 0, 0);
    }
  }

  #pragma unroll
  for (int rg = 0; rg < 2; ++rg) {
    const size_t row = (size_t)(r0 + rg * 16 + c);
    #pragma unroll
    for (int nt = 0; nt < 6; ++nt) {
      floatx4 bia = *(const floatx4*)(b2 + nt * 16 + q * 4);
      half4 yy;
      #pragma unroll
      for (int r = 0; r < 4; ++r)
        yy[r] = (_Float16)((acc2[rg][nt][r] + bia[r]) * sg[rg]);
      *(half4*)(Yc + row * 96 + nt * 16 + q * 4) = yy;
    }
  }
}

// Variable-node MLP, same register-direct structure. Gathers Yc via perm
// (B-frags), scatters Mc via perm in packed 8B chunks, emits llr (out col 48).
__global__ __launch_bounds__(256, 4) void kernelV(
    const _Float16* __restrict__ Yc, const int* __restrict__ perm,
    const float* __restrict__ prior,
    _Float16* __restrict__ Mc, float* __restrict__ outp,
    const _Float16* __restrict__ W1p, const _Float16* __restrict__ W2p,
    const float* __restrict__ b1, const float* __restrict__ b2)
{
  const int tid = threadIdx.x, w = tid >> 6, l = tid & 63;
  const int q = l >> 4, c = l & 15;
  const int r0 = blockIdx.x * 128 + w * 32;
  const int b  = r0 >> 10;
  const int v0 = r0 & 1023;
  const size_t yb = (size_t)b * EDGE;

  // Xv^T fragments: lane holds var-row n = l&15, k = q*8+j (K=64: 48 msgs + prior + pad)
  half8 mb[2][2];
  #pragma unroll
  for (int rg = 0; rg < 2; ++rg) {
    int v = v0 + rg * 16 + c;
    int e0 = perm[3 * v + (q >> 1)];
    mb[rg][0] = *(const half8*)(Yc + (yb + e0) * 16 + (q & 1) * 8);
    half8 m1 = {0,0,0,0,0,0,0,0};
    if (q < 2) {
      int e2 = perm[3 * v + 2];
      m1 = *(const half8*)(Yc + (yb + e2) * 16 + q * 8);
    } else if (q == 2) {
      m1[0] = (_Float16)prior[v];
    }
    mb[rg][1] = m1;
  }

  floatx4 acc2[2][4];
  #pragma unroll
  for (int rg = 0; rg < 2; ++rg)
    #pragma unroll
    for (int nt = 0; nt < 4; ++nt)
      acc2[rg][nt] = (floatx4){0.f, 0.f, 0.f, 0.f};

  const half8* W1f = (const half8*)W1p;
  const half4* W2f = (const half4*)W2p;

  #pragma unroll 2
  for (int ht = 0; ht < NT1V; ++ht) {
    half8 wa0 = W1f[(0 * NT1V + ht) * 64 + l];
    half8 wa1 = W1f[(1 * NT1V + ht) * 64 + l];
    half4 wf[4];
    #pragma unroll
    for (int nt = 0; nt < 4; ++nt)
      wf[nt] = W2f[(ht * NT2V + nt) * 64 + l];
    floatx4 bia = *(const floatx4*)(b1 + ht * 16 + q * 4);
    #pragma unroll
    for (int rg = 0; rg < 2; ++rg) {
      floatx4 a = {0.f, 0.f, 0.f, 0.f};
      a = __builtin_amdgcn_mfma_f32_16x16x32_f16(wa0, mb[rg][0], a, 0, 0, 0);
      a = __builtin_amdgcn_mfma_f32_16x16x32_f16(wa1, mb[rg][1], a, 0, 0, 0);
      half4 h;
      #pragma unroll
      for (int r = 0; r < 4; ++r)
        h[r] = (_Float16)gelu_f(a[r] + bia[r]);
      #pragma unroll
      for (int nt = 0; nt < 4; ++nt)
        acc2[rg][nt] = __builtin_amdgcn_mfma_f32_16x16x16f16(wf[nt], h, acc2[rg][nt], 0, 0, 0);
    }
  }

  const float bllr = b2[48];
  #pragma unroll
  for (int rg = 0; rg < 2; ++rg) {
    int v = v0 + rg * 16 + c;
    #pragma unroll
    for (int nt = 0; nt < 3; ++nt) {
      int pe = perm[3 * v + nt];
      floatx4 bia = *(const floatx4*)(b2 + nt * 16 + q * 4);
      half4 yy;
      #pragma unroll
      for (int r = 0; r < 4; ++r)
        yy[r] = (_Float16)(acc2[rg][nt][r] + bia[r]);
      *(half4*)(Mc + (yb + pe) * 16 + q * 4) = yy;
    }
    if (q == 0)
      outp[r0 + rg * 16 + c] = acc2[rg][3][0] + bllr;
  }
}

extern "C" void kernel_launch(void* const* d_in, const int* in_sizes, int n_in,
                              void* d_out, int out_size, void* d_ws, size_t ws_size,
                              hipStream_t stream)
{
  const int*   synd  = (const int*)d_in[0];
  const float* prior = (const float*)d_in[2];
  const int*   perm  = (const int*)d_in[3];
  const float* cW1 = (const float*)d_in[4];
  const float* cb1 = (const float*)d_in[5];
  const float* cW2 = (const float*)d_in[6];
  const float* cb2 = (const float*)d_in[7];
  const float* vW1 = (const float*)d_in[8];
  const float* vb1 = (const float*)d_in[9];
  const float* vW2 = (const float*)d_in[10];
  const float* vb2 = (const float*)d_in[11];
  float* outp = (float*)d_out;
  const int T = out_size / (BATCH * NVAR);

  char* p = (char*)d_ws;
  _Float16* Mc  = (_Float16*)p; p += (size_t)BATCH * EDGE * 16 * 2;
  _Float16* Yc  = (_Float16*)p; p += (size_t)BATCH * EDGE * 16 * 2;
  _Float16* w1c = (_Float16*)p; p += (size_t)KS1C * NT1C * 64 * 8 * 2;
  _Float16* w2c = (_Float16*)p; p += (size_t)NT1C * NT2C * 64 * 4 * 2;
  _Float16* w1v = (_Float16*)p; p += (size_t)KS1V * NT1V * 64 * 8 * 2;
  _Float16* w2v = (_Float16*)p; p += (size_t)NT1V * NT2V * 64 * 4 * 2;
  float* b1c  = (float*)p; p += 416 * 4;
  float* w96c = (float*)p; p += 416 * 4;
  float* b2c  = (float*)p; p += 96 * 4;
  float* b1v  = (float*)p; p += 208 * 4;
  float* b2v  = (float*)p; p += 64 * 4;

  const int packN = KS1C * NT1C * 64 + NT1C * NT2C * 64 + KS1V * NT1V * 64 +
                    NT1V * NT2V * 64 + 416 + 416 + 96 + 208 + 64;   // 21168
  pack_kernel<<<(packN + 255) / 256, 256, 0, stream>>>(
      cW1, cb1, cW2, cb2, vW1, vb1, vW2, vb2,
      w1c, w2c, w1v, w2v, b1c, w96c, b2c, b1v, b2v);
  init_kernel<<<(BATCH * EDGE) / 256, 256, 0, stream>>>(perm, prior, Mc);

  for (int t = 0; t < T; ++t) {
    kernelC<<<(BATCH * NCHK) / 128, 256, 0, stream>>>(
        Mc, synd, Yc, w1c, w2c, b1c, w96c, b2c);
    kernelV<<<(BATCH * NVAR) / 128, 256, 0, stream>>>(
        Yc, perm, prior, Mc, outp + (size_t)t * BATCH * NVAR, w1v, w2v, b1v, b2v);
  }
}